// Round 6
// baseline (2598.092 us; speedup 1.0000x reference)
//
#include <hip/hip_runtime.h>
#include <cstdint>
#include <cstddef>

typedef __bf16 bf16;
typedef __bf16 bf16x8 __attribute__((ext_vector_type(8)));
typedef __bf16 bf16x4 __attribute__((ext_vector_type(4)));
typedef float f32x4 __attribute__((ext_vector_type(4)));
typedef unsigned u32x4 __attribute__((ext_vector_type(4)));

#define B_ 64
#define S_ 512
#define E_ 512
#define H_ 1024
#define C_ 20
#define EH 1536   // E+H
#define G4 4096   // 4*H

// ---- workspace layout (bytes) ----
static const size_t OFF_WCAT  = 0;              // bf16 [4096][1536] = 12,582,912
static const size_t OFF_BIAS4 = 12582912;       // f32  [4096]       = 16,384
static const size_t OFF_AT0   = 12599296;       // u32x4 [64][256] tagged granules = 262,144
static const size_t OFF_AT1   = 12861440;       // u32x4 [64][256]   = 262,144
static const size_t OFF_CST   = 13123584;       // f32  [64][1024]   = 262,144
static const size_t OFF_LOSS  = 13385728;       // f32  [64]         = 256
static const size_t OFF_GX    = 13385984;       // bf16 [TC*64][4096] = TC*524,288
static const size_t STATE_BYTES = OFF_GX - OFF_AT0;   // 786,688 (zeroed each call)

__device__ inline float sigmoidf_(float x) { return 1.0f / (1.0f + __expf(-x)); }
__device__ inline float tanh_fast(float x) {
  float ax = fabsf(x);
  float e = __expf(-2.0f * ax);
  float t = (1.0f - e) / (1.0f + e);
  return copysignf(t, x);
}
__device__ inline float bf2f(unsigned lo16) {
  const unsigned u = lo16 << 16;
  return __builtin_bit_cast(float, u);
}

// coherent 16B ops: bypass L1/L2, hit the MALL coherence point directly.
__device__ inline void load_coh16(u32x4* dst, const void* p) {
  asm volatile("global_load_dwordx4 %0, %1, off sc0 sc1"
               : "=v"(*dst) : "v"(p) : "memory");
}
__device__ inline void store_coh16(void* p, u32x4 v) {
  asm volatile("global_store_dwordx4 %0, %1, off sc0 sc1"
               :: "v"(p), "v"(v) : "memory");
}

// ---- zero at0/at1/cst/loss (contiguous state region; resets tags per call) ----
__global__ __launch_bounds__(256) void init_misc(uint4* st) {
  const int n = (int)(STATE_BYTES / 16);   // 49,168
  for (int idx = blockIdx.x * 256 + threadIdx.x; idx < n; idx += gridDim.x * 256)
    st[idx] = uint4{0u, 0u, 0u, 0u};
}

// ---- convert gate weights to bf16, rows r = h*4+g (h-major, gate minor) ----
__global__ __launch_bounds__(256) void convert_w(
    const float* __restrict__ Wf, const float* __restrict__ Wi,
    const float* __restrict__ Wc, const float* __restrict__ Wo,
    const float* __restrict__ bfp, const float* __restrict__ bip,
    const float* __restrict__ bcp, const float* __restrict__ bop,
    bf16* __restrict__ Wcat, float* __restrict__ bias4)
{
  const int total = G4 * (EH / 8);   // 786,432 chunks of 8
  for (int idx = blockIdx.x * 256 + threadIdx.x; idx < total; idx += gridDim.x * 256) {
    const int r = idx / 192;
    const int ck = idx - r * 192;
    const int g = r & 3, h = r >> 2;
    const float* W = (g == 0) ? Wf : (g == 1) ? Wi : (g == 2) ? Wc : Wo;
    const float* src = W + (size_t)h * EH + ck * 8;
    const float4 v0 = *(const float4*)src;
    const float4 v1 = *(const float4*)(src + 4);
    bf16x8 o;
    o[0] = (bf16)v0.x; o[1] = (bf16)v0.y; o[2] = (bf16)v0.z; o[3] = (bf16)v0.w;
    o[4] = (bf16)v1.x; o[5] = (bf16)v1.y; o[6] = (bf16)v1.z; o[7] = (bf16)v1.w;
    *(bf16x8*)(Wcat + (size_t)r * EH + ck * 8) = o;
    if (ck == 0) {
      const float* Bp = (g == 0) ? bfp : (g == 1) ? bip : (g == 2) ? bcp : bop;
      bias4[r] = Bp[h];
    }
  }
}

// ---- gx_chunk[ml][r] = sum_k emb[x[m]][k] * Wcat[r][k], K = 512 (x-part) ----
__global__ __launch_bounds__(256) void gemm_gx(
    const int* __restrict__ x, const float* __restrict__ emb,
    const bf16* __restrict__ Wcat, bf16* __restrict__ gx, int t0)
{
  __shared__ char As[16384];
  __shared__ char Bs[16384];
  const int t = threadIdx.x;
  const int lane = t & 63, wid = t >> 6;
  const int wm = wid >> 1, wn = wid & 1;
  const int bm = blockIdx.x >> 5;
  const int bn = blockIdx.x & 31;
  const int m0l = bm * 128, n0 = bn * 128;
  f32x4 acc[4][4] = {};
  const int srow = t >> 3, sc16 = t & 7;
  for (int k0 = 0; k0 < E_; k0 += 64) {
    __syncthreads();
    #pragma unroll
    for (int i = 0; i < 4; ++i) {
      const int row = i * 32 + srow;
      const int cs = sc16 ^ (row & 7);     // pre-swizzled source chunk
      const int m = t0 * 64 + m0l + row;
      const int tok = x[(m & 63) * S_ + (m >> 6)];
      const float* srcA = emb + (size_t)tok * E_ + k0 + cs * 8;
      const float4 a0v = *(const float4*)srcA;
      const float4 a1v = *(const float4*)(srcA + 4);
      bf16x8 oa;
      oa[0] = (bf16)a0v.x; oa[1] = (bf16)a0v.y; oa[2] = (bf16)a0v.z; oa[3] = (bf16)a0v.w;
      oa[4] = (bf16)a1v.x; oa[5] = (bf16)a1v.y; oa[6] = (bf16)a1v.z; oa[7] = (bf16)a1v.w;
      *(bf16x8*)(As + row * 128 + sc16 * 16) = oa;
      const uint4 vb = *(const uint4*)(Wcat + (size_t)(n0 + row) * EH + k0 + cs * 8);
      *(uint4*)(Bs + row * 128 + sc16 * 16) = vb;
    }
    __syncthreads();
    #pragma unroll
    for (int ks = 0; ks < 64; ks += 32) {
      const int kb = (ks + ((lane >> 4) * 8)) * 2;
      bf16x8 af[4], bfr[4];
      #pragma unroll
      for (int mt = 0; mt < 4; ++mt) {
        const int ra = wm * 64 + mt * 16 + (lane & 15);
        af[mt] = *(const bf16x8*)(As + ra * 128 + (kb ^ ((ra & 7) << 4)));
      }
      #pragma unroll
      for (int nt = 0; nt < 4; ++nt) {
        const int rb = wn * 64 + nt * 16 + (lane & 15);
        bfr[nt] = *(const bf16x8*)(Bs + rb * 128 + (kb ^ ((rb & 7) << 4)));
      }
      #pragma unroll
      for (int mt = 0; mt < 4; ++mt)
        #pragma unroll
        for (int nt = 0; nt < 4; ++nt)
          acc[mt][nt] = __builtin_amdgcn_mfma_f32_16x16x32_bf16(af[mt], bfr[nt], acc[mt][nt], 0, 0, 0);
    }
  }
  const int cb = (lane >> 4) * 4;
  #pragma unroll
  for (int mt = 0; mt < 4; ++mt) {
    #pragma unroll
    for (int r = 0; r < 4; ++r) {
      const int mrow = m0l + wm * 64 + mt * 16 + cb + r;   // chunk-local row
      bf16* dst = gx + (size_t)mrow * G4 + n0 + wn * 64 + (lane & 15);
      #pragma unroll
      for (int nt = 0; nt < 4; ++nt)
        dst[nt * 16] = (bf16)acc[mt][nt][r];
    }
  }
}

// ---- persistent LSTM recurrence over steps [t0, t0+tc) ----
// 256 WGs = 4 batch-groups (16 batches) x 64 hidden-slice WGs (16 h each).
// R6 tagged-granule protocol: out(s) lives in buffer (s+1)&1 as 16B granules
// {bf16 v0..v3, tag=s+1, 0} stored with one dwordx4 sc0 sc1 (atomic unit:
// tag travels with data). Consumer at step s polls its granules for tag==s.
// No flags, no drains. Depth-2 ring safety: WG publishes s only after its 4
// waves (joined by the one barrier) consumed all 64 producers' s-1 granules
// => all published s-1 => all consumed s-2 => overwrite safe. Same-thread
// same-address store ordering: each step's poll does vmcnt(0), draining the
// thread's previous-round store. Tags are global step numbers (chunk-safe);
// init_misc re-zeroes them each call (graph-replay safe).
__global__ __launch_bounds__(256, 1) void lstm_rec(
    const bf16* __restrict__ Wcat, const float* __restrict__ bias4,
    const bf16* __restrict__ gx, unsigned* __restrict__ at0,
    unsigned* __restrict__ at1, float* __restrict__ cstg,
    int t0, int tc)
{
  __shared__ __align__(16) float accs[2][4][16][68];   // parity double-buffer
  const int t = threadIdx.x;
  const int lane = t & 63;
  const int w = t >> 6;                     // wave id = K-quarter
  const int bid = blockIdx.x;
  const int grp = bid & 3;                  // batch group (16 batches)
  const int hwg = bid >> 2;                 // 0..63 hidden slice
  const int h0 = hwg * 16;
  const int l15 = lane & 15;
  const int kq8 = (lane >> 4) * 8;          // k sub-offset within a 32-chunk

  // --- preload W B-fragments: 64 gate rows x my K-quarter (256 cols) ---
  bf16x8 wf[32];                            // static-indexed -> regs/AGPRs
  {
    const bf16* wbase = Wcat + (size_t)(h0 * 4 + l15) * EH + 512 + w * 256 + kq8;
    #pragma unroll
    for (int nt = 0; nt < 4; ++nt)
      #pragma unroll
      for (int i = 0; i < 8; ++i)
        wf[nt * 8 + i] = *(const bf16x8*)(wbase + (size_t)nt * 16 * EH + i * 32);
  }
  const int j   = t & 15;                   // hidden unit within slice
  const int blb = t >> 4;                   // batch within group (reduce phase)
  const float4 bias = *(const float4*)(bias4 + (h0 + j) * 4);
  const int bg0 = grp * 16 + blb;
  float cst = cstg[(size_t)bg0 * H_ + h0 + j];
  // consumer granule base: batch (grp*16+l15), granule (w*64 + (lane>>4)*2 + i*8)
  const size_t aboff = ((size_t)(grp * 16 + l15) * 256 + (size_t)(w * 64 + (lane >> 4) * 2)) * 4;
  // producer granule: [bg0][(h0>>2) + (j>>2)], stored by j%4==0 lanes
  const size_t pgoff = ((size_t)bg0 * 256 + (size_t)((h0 >> 2) + (j >> 2))) * 4;

  for (int s = 0; s < tc; ++s) {
    const int step = t0 + s;
    const unsigned exp_tag = (unsigned)step;        // tag of out(step-1)
    const unsigned* aprev = (step & 1) ? at1 : at0; // buffer step&1 holds out(step-1)
    unsigned* anext = (step & 1) ? at0 : at1;
    // gx for this step (plain cached load; drains with the poll's vmcnt)
    const bf16x4 g0 = *(const bf16x4*)(gx + (size_t)s * (B_ * G4) + (size_t)bg0 * G4 + (h0 + j) * 4);

    // --- tagged poll: accept when all 16 granules carry tag==step ---
    const unsigned* abase = aprev + aboff;
    u32x4 g[16];
    for (;;) {
      #pragma unroll
      for (int i = 0; i < 8; ++i) {
        load_coh16(&g[2 * i],     abase + i * 32);
        load_coh16(&g[2 * i + 1], abase + i * 32 + 4);
      }
      asm volatile("s_waitcnt vmcnt(0)" ::: "memory");
      __builtin_amdgcn_sched_barrier(0);
      int ok = 1;
      #pragma unroll
      for (int i = 0; i < 16; ++i) ok &= (g[i].z == exp_tag) ? 1 : 0;
      if (__all(ok)) break;
    }
    __builtin_amdgcn_sched_barrier(0);

    // --- MFMA over my K-quarter ---
    f32x4 pacc[4] = {};
    #pragma unroll
    for (int i = 0; i < 8; ++i) {
      u32x4 mg;
      mg.x = g[2 * i].x; mg.y = g[2 * i].y;
      mg.z = g[2 * i + 1].x; mg.w = g[2 * i + 1].y;
      const bf16x8 a8 = __builtin_bit_cast(bf16x8, mg);
      #pragma unroll
      for (int nt = 0; nt < 4; ++nt)
        pacc[nt] = __builtin_amdgcn_mfma_f32_16x16x32_bf16(a8, wf[nt * 8 + i], pacc[nt], 0, 0, 0);
    }
    // --- cross-wave K-reduction via parity LDS (single barrier per step) ---
    const int par = step & 1;
    {
      const int m0 = (lane >> 4) * 4;
      #pragma unroll
      for (int nt = 0; nt < 4; ++nt)
        #pragma unroll
        for (int r = 0; r < 4; ++r)
          accs[par][w][m0 + r][nt * 16 + l15] = pacc[nt][r];
    }
    __syncthreads();
    const float4 q0 = *(const float4*)&accs[par][0][blb][j * 4];
    const float4 q1 = *(const float4*)&accs[par][1][blb][j * 4];
    const float4 q2 = *(const float4*)&accs[par][2][blb][j * 4];
    const float4 q3 = *(const float4*)&accs[par][3][blb][j * 4];
    float hv;
    {
      const float pf = q0.x + q1.x + q2.x + q3.x + (float)g0[0] + bias.x;
      const float pi = q0.y + q1.y + q2.y + q3.y + (float)g0[1] + bias.y;
      const float pc = q0.z + q1.z + q2.z + q3.z + (float)g0[2] + bias.z;
      const float po = q0.w + q1.w + q2.w + q3.w + (float)g0[3] + bias.w;
      const float fg = sigmoidf_(pf), ig = sigmoidf_(pi), og = sigmoidf_(po);
      cst = fg * cst + ig * tanh_fast(pc);
      hv = tanh_fast(cst) * og;
    }
    // --- tagged publish: one dwordx4 per 4 h-units (j%4==0 lanes) ---
    {
      const unsigned me = (unsigned)__builtin_bit_cast(unsigned short, (bf16)hv);
      const unsigned pr  = me | (__shfl_down(me, 1) << 16);
      const unsigned pr2 = __shfl_down(pr, 2);
      if ((j & 3) == 0) {
        u32x4 outq;
        outq.x = pr; outq.y = pr2; outq.z = (unsigned)(step + 1); outq.w = 0u;
        store_coh16(anext + pgoff, outq);
      }
    }
  }
  cstg[(size_t)bg0 * H_ + h0 + j] = cst;
}

// ---- logits + per-batch loss (reads tagged final state, strips tags) ----
__global__ __launch_bounds__(256) void logits_loss(
    const unsigned* __restrict__ at, const float* __restrict__ Wv,
    const float* __restrict__ bv, const int* __restrict__ label,
    float* __restrict__ lossa)
{
  const int b = blockIdx.x;
  const int t = threadIdx.x;
  const int lane = t & 63, wid = t >> 6;
  const u32x4 gv = *(const u32x4*)(at + ((size_t)b * 256 + t) * 4);
  const float av0 = bf2f(gv.x & 0xffffu), av1 = bf2f(gv.x >> 16);
  const float av2 = bf2f(gv.y & 0xffffu), av3 = bf2f(gv.y >> 16);
  float part[C_];
  #pragma unroll
  for (int c = 0; c < C_; ++c) {
    const float4 w = *(const float4*)(Wv + (size_t)c * H_ + t * 4);
    part[c] = av0 * w.x + av1 * w.y + av2 * w.z + av3 * w.w;
  }
  #pragma unroll
  for (int off = 32; off > 0; off >>= 1) {
    #pragma unroll
    for (int c = 0; c < C_; ++c) part[c] += __shfl_down(part[c], off);
  }
  __shared__ float red[4][C_];
  __shared__ float lg[C_];
  if (lane == 0) {
    #pragma unroll
    for (int c = 0; c < C_; ++c) red[wid][c] = part[c];
  }
  __syncthreads();
  if (t < C_) lg[t] = red[0][t] + red[1][t] + red[2][t] + red[3][t] + bv[t];
  __syncthreads();
  if (t == 0) {
    float m = lg[0];
    for (int c = 1; c < C_; ++c) m = fmaxf(m, lg[c]);
    float se = 0.0f;
    for (int c = 0; c < C_; ++c) se += __expf(lg[c] - m);
    const float lse = logf(se) + m;
    lossa[b] = lse - lg[label[b]];
  }
}

__global__ __launch_bounds__(64) void loss_mean(const float* __restrict__ lossa,
                                                float* __restrict__ out) {
  const int t = threadIdx.x;
  float v = lossa[t];
  #pragma unroll
  for (int off = 32; off > 0; off >>= 1) v += __shfl_down(v, off);
  if (t == 0) out[0] = v * (1.0f / 64.0f);
}

extern "C" void kernel_launch(void* const* d_in, const int* in_sizes, int n_in,
                              void* d_out, int out_size, void* d_ws, size_t ws_size,
                              hipStream_t stream) {
  const int*   x     = (const int*)d_in[0];
  const int*   label = (const int*)d_in[1];
  const float* emb   = (const float*)d_in[2];
  const float* Wf    = (const float*)d_in[3];
  const float* bfp   = (const float*)d_in[4];
  const float* Wi    = (const float*)d_in[5];
  const float* bip   = (const float*)d_in[6];
  const float* Wc    = (const float*)d_in[7];
  const float* bcp   = (const float*)d_in[8];
  const float* Wo    = (const float*)d_in[9];
  const float* bop   = (const float*)d_in[10];
  const float* Wv    = (const float*)d_in[11];
  const float* bv    = (const float*)d_in[12];
  (void)in_sizes; (void)n_in; (void)out_size;

  // Pick the largest time-chunk TC whose gx buffer fits the workspace.
  int TC = 0;
  const size_t avail = (ws_size > OFF_GX) ? (ws_size - OFF_GX) : 0;
  const int cands[7] = {512, 256, 128, 64, 32, 16, 8};
  for (int i = 0; i < 7; ++i) {
    if ((size_t)cands[i] * 524288 <= avail) { TC = cands[i]; break; }
  }
  if (TC == 0) return;   // ws < ~17.6 MB — cannot run this design

  char* ws = (char*)d_ws;
  bf16*     Wcat  = (bf16*)(ws + OFF_WCAT);
  float*    bias4 = (float*)(ws + OFF_BIAS4);
  unsigned* at0   = (unsigned*)(ws + OFF_AT0);
  unsigned* at1   = (unsigned*)(ws + OFF_AT1);
  float*    cstg  = (float*)(ws + OFF_CST);
  float*    lossa = (float*)(ws + OFF_LOSS);
  bf16*     gx    = (bf16*)(ws + OFF_GX);

  init_misc<<<64, 256, 0, stream>>>((uint4*)(ws + OFF_AT0));
  convert_w<<<1024, 256, 0, stream>>>(Wf, Wi, Wc, Wo, bfp, bip, bcp, bop, Wcat, bias4);
  const int nchunks = S_ / TC;
  for (int c = 0; c < nchunks; ++c) {
    const int t0 = c * TC;
    gemm_gx<<<(TC / 2) * 32, 256, 0, stream>>>(x, emb, Wcat, gx, t0);
    lstm_rec<<<256, 256, 0, stream>>>(Wcat, bias4, gx, at0, at1, cstg, t0, TC);
  }
  // final state = out(511), buffer (511+1)&1 = 0 -> at0
  logits_loss<<<64, 256, 0, stream>>>(at0, Wv, bv, label, lossa);
  loss_mean<<<1, 64, 0, stream>>>(lossa, (float*)d_out);
}